// Round 1
// baseline (1545.805 us; speedup 1.0000x reference)
//
#include <hip/hip_runtime.h>
#include <hip/hip_bf16.h>

// MHA: B=16 T=1024 C=384 H=6 D=64, fp32 everywhere.
// ws layout (floats): q[16*6*1024*64] | k[same] | v[same] | attn[16*1024*384]
// total = 4 * 6291456 floats = 100,663,296 bytes required in d_ws.

#define Bn 16
#define Tn 1024
#define Cn 384
#define Hn 6
#define Dn 64
#define Mn (Bn*Tn)

__device__ __forceinline__ float4 ld4(const float* p) { return *reinterpret_cast<const float4*>(p); }
__device__ __forceinline__ void st4(float* p, float4 v) { *reinterpret_cast<float4*>(p) = v; }

// ---------------- Kernel 1: fused QKV projection ----------------
// x:[M,C] row-major; wq/wk/wv:[H][C][D]; outputs q/k/v:[B,H,T,D]
// grid (M/64, 3*H), block 256. 64x64 tile, 4x4 per-thread micro-tile, BK=16.
__global__ __launch_bounds__(256) void qkv_proj(
    const float* __restrict__ x, const float* __restrict__ wq,
    const float* __restrict__ wk, const float* __restrict__ wv,
    float* __restrict__ qo, float* __restrict__ ko, float* __restrict__ vo)
{
    __shared__ float As[16][64];   // [k][m]
    __shared__ float Bs[16][64];   // [k][n]
    const int t  = threadIdx.x;
    const int tx = t & 15, ty = t >> 4;
    const int m0 = blockIdx.x * 64;
    const int mat = blockIdx.y / Hn;
    const int h   = blockIdx.y % Hn;
    const float* w = (mat == 0 ? wq : mat == 1 ? wk : wv) + (size_t)h * Cn * Dn;
    float* op = (mat == 0 ? qo : mat == 1 ? ko : vo);

    const int arow = t >> 2;   // 0..63
    const int akq  = t & 3;    // float4 index along k
    const int bk   = t >> 4;   // 0..15
    const int bd4  = t & 15;   // 0..15

    float acc[4][4] = {};
    for (int k0 = 0; k0 < Cn; k0 += 16) {
        float4 av = ld4(&x[(size_t)(m0 + arow) * Cn + k0 + akq * 4]);
        float4 bv = ld4(&w[(size_t)(k0 + bk) * Dn + bd4 * 4]);
        __syncthreads();
        As[akq*4+0][arow] = av.x;
        As[akq*4+1][arow] = av.y;
        As[akq*4+2][arow] = av.z;
        As[akq*4+3][arow] = av.w;
        st4(&Bs[bk][bd4*4], bv);
        __syncthreads();
        #pragma unroll
        for (int k = 0; k < 16; ++k) {
            float4 a4 = ld4(&As[k][ty*4]);
            float4 b4 = ld4(&Bs[k][tx*4]);
            float a[4] = {a4.x, a4.y, a4.z, a4.w};
            float b[4] = {b4.x, b4.y, b4.z, b4.w};
            #pragma unroll
            for (int i = 0; i < 4; ++i)
                #pragma unroll
                for (int j = 0; j < 4; ++j)
                    acc[i][j] = fmaf(a[i], b[j], acc[i][j]);
        }
    }
    #pragma unroll
    for (int i = 0; i < 4; ++i) {
        int m = m0 + ty*4 + i;
        int b = m >> 10, tl = m & 1023;
        st4(&op[(((size_t)b*Hn + h)*Tn + tl)*Dn + tx*4],
            make_float4(acc[i][0], acc[i][1], acc[i][2], acc[i][3]));
    }
}

// ---------------- Kernel 2: flash attention (no mask), scale 1/sqrt(384) ----
// grid = B*H*(T/64) blocks, 256 threads. Per block: 64 Q rows, loop K/V tiles of 64.
// LDS tiles are [64][64] with 16B-slot XOR swizzle: slot' = slot ^ (row>>2)
// -> all ds_read_b128 patterns <=2-way.  KPs holds K during S, P during PV.
__global__ __launch_bounds__(256) void attn_fwd(
    const float* __restrict__ q, const float* __restrict__ k, const float* __restrict__ v,
    float* __restrict__ ao)
{
    __shared__ float Qs[64][64];
    __shared__ float KPs[64][64];
    __shared__ float VsT[64][64];   // [d][s]
    __shared__ float mrow[64];
    __shared__ float lrow[64];

    const int t  = threadIdx.x;
    const int tx = t & 15, ty = t >> 4;
    const int bh = blockIdx.x >> 4;   // b*H + h
    const int qt = blockIdx.x & 15;
    const float* qb = q + (size_t)bh * Tn * Dn + (size_t)qt * 64 * Dn;
    const float* kb = k + (size_t)bh * Tn * Dn;
    const float* vb = v + (size_t)bh * Tn * Dn;
    const float scale = 0.051031036307982884f;  // 1/sqrt(384)

    #pragma unroll
    for (int u = 0; u < 4; ++u) {               // load+scale Q tile
        int f = u * 256 + t;
        int row = f >> 4, c4 = f & 15;
        float4 v4 = ld4(&qb[(size_t)row * Dn + c4 * 4]);
        v4.x *= scale; v4.y *= scale; v4.z *= scale; v4.w *= scale;
        st4(&Qs[row][((c4 ^ (row >> 2)) & 15) * 4], v4);
    }
    if (tx == 0) {
        #pragma unroll
        for (int i = 0; i < 4; ++i) { mrow[ty*4+i] = -1e30f; lrow[ty*4+i] = 0.f; }
    }

    float o[4][4] = {};

    for (int kt = 0; kt < Tn/64; ++kt) {
        __syncthreads();                         // prev tile fully consumed
        #pragma unroll
        for (int u = 0; u < 4; ++u) {            // load K, V(transposed)
            int f = u * 256 + t;
            int row = f >> 4, c4 = f & 15;
            float4 kv = ld4(&kb[((size_t)kt*64 + row) * Dn + c4 * 4]);
            st4(&KPs[row][((c4 ^ (row >> 2)) & 15) * 4], kv);
            float4 vv = ld4(&vb[((size_t)kt*64 + row) * Dn + c4 * 4]);
            int scol = ((((row >> 2) ^ c4) & 15) << 2) | (row & 3);
            VsT[c4*4+0][scol] = vv.x;
            VsT[c4*4+1][scol] = vv.y;
            VsT[c4*4+2][scol] = vv.z;
            VsT[c4*4+3][scol] = vv.w;
        }
        __syncthreads();
        // S = Q K^T : rows 4ty+i, cols 4tx+j
        float s_[4][4] = {};
        #pragma unroll
        for (int s4 = 0; s4 < 16; ++s4) {
            float4 a4[4], b4[4];
            #pragma unroll
            for (int i = 0; i < 4; ++i) a4[i] = ld4(&Qs[ty*4+i][((s4 ^ ty) & 15) * 4]);
            #pragma unroll
            for (int j = 0; j < 4; ++j) b4[j] = ld4(&KPs[tx*4+j][((s4 ^ tx) & 15) * 4]);
            #pragma unroll
            for (int i = 0; i < 4; ++i)
                #pragma unroll
                for (int j = 0; j < 4; ++j) {
                    s_[i][j] = fmaf(a4[i].x, b4[j].x, s_[i][j]);
                    s_[i][j] = fmaf(a4[i].y, b4[j].y, s_[i][j]);
                    s_[i][j] = fmaf(a4[i].z, b4[j].z, s_[i][j]);
                    s_[i][j] = fmaf(a4[i].w, b4[j].w, s_[i][j]);
                }
        }
        __syncthreads();                         // all waves done reading K
        // online softmax; P overwrites K buffer (own rows only -> same-wave)
        #pragma unroll
        for (int i = 0; i < 4; ++i) {
            int r = ty*4 + i;
            float rm = fmaxf(fmaxf(s_[i][0], s_[i][1]), fmaxf(s_[i][2], s_[i][3]));
            rm = fmaxf(rm, __shfl_xor(rm, 1));
            rm = fmaxf(rm, __shfl_xor(rm, 2));
            rm = fmaxf(rm, __shfl_xor(rm, 4));
            rm = fmaxf(rm, __shfl_xor(rm, 8));
            float mold = mrow[r];
            float mnew = fmaxf(mold, rm);
            float p0 = __expf(s_[i][0] - mnew);
            float p1 = __expf(s_[i][1] - mnew);
            float p2 = __expf(s_[i][2] - mnew);
            float p3 = __expf(s_[i][3] - mnew);
            float rs = p0 + p1 + p2 + p3;
            rs += __shfl_xor(rs, 1);
            rs += __shfl_xor(rs, 2);
            rs += __shfl_xor(rs, 4);
            rs += __shfl_xor(rs, 8);
            float fct = __expf(mold - mnew);
            #pragma unroll
            for (int j = 0; j < 4; ++j) o[i][j] *= fct;
            if (tx == 0) { mrow[r] = mnew; lrow[r] = lrow[r] * fct + rs; }
            st4(&KPs[r][((tx ^ ty) & 15) * 4], make_float4(p0, p1, p2, p3));
        }
        // PV: o[i][j] += sum_s P[r][s] * V[s][4tx+j]
        #pragma unroll
        for (int s4 = 0; s4 < 16; ++s4) {
            float4 p4[4], v4[4];
            #pragma unroll
            for (int i = 0; i < 4; ++i) p4[i] = ld4(&KPs[ty*4+i][((s4 ^ ty) & 15) * 4]);
            #pragma unroll
            for (int j = 0; j < 4; ++j) v4[j] = ld4(&VsT[tx*4+j][((s4 ^ tx) & 15) * 4]);
            #pragma unroll
            for (int i = 0; i < 4; ++i)
                #pragma unroll
                for (int j = 0; j < 4; ++j) {
                    o[i][j] = fmaf(p4[i].x, v4[j].x, o[i][j]);
                    o[i][j] = fmaf(p4[i].y, v4[j].y, o[i][j]);
                    o[i][j] = fmaf(p4[i].z, v4[j].z, o[i][j]);
                    o[i][j] = fmaf(p4[i].w, v4[j].w, o[i][j]);
                }
        }
    }
    // epilogue: normalize, write attn out as [B,T,H*D]
    const int b = bh / Hn, h = bh % Hn;
    #pragma unroll
    for (int i = 0; i < 4; ++i) {
        int r = ty*4 + i;
        float inv = 1.0f / lrow[r];
        int tl = qt*64 + r;
        st4(&ao[((size_t)(b*Tn + tl)) * Cn + h*Dn + tx*4],
            make_float4(o[i][0]*inv, o[i][1]*inv, o[i][2]*inv, o[i][3]*inv));
    }
}

// ---------------- Kernel 3: output projection + bias ----------------
// out[m,j] = sum_i attn[m,i]*wp[j,i] + bp[j].  B-tile loaded transposed with
// XOR swizzle (reads b128 along n would otherwise 16-way conflict).
__global__ __launch_bounds__(256) void out_proj(
    const float* __restrict__ a, const float* __restrict__ wpm,
    const float* __restrict__ bp, float* __restrict__ out)
{
    __shared__ float As[16][64];
    __shared__ float Bs[16][64];
    const int t  = threadIdx.x;
    const int tx = t & 15, ty = t >> 4;
    const int m0 = blockIdx.x * 64;
    const int n0 = blockIdx.y * 64;
    const int arow = t >> 2, akq = t & 3;
    const int bkk = t & 15, bn = t >> 4;    // bkk = k, bn = base n

    float acc[4][4] = {};
    for (int k0 = 0; k0 < Cn; k0 += 16) {
        float4 av = ld4(&a[(size_t)(m0 + arow) * Cn + k0 + akq * 4]);
        float bvals[4];
        #pragma unroll
        for (int u = 0; u < 4; ++u)
            bvals[u] = wpm[(size_t)(n0 + bn + u*16) * Cn + k0 + bkk];
        __syncthreads();
        As[akq*4+0][arow] = av.x;
        As[akq*4+1][arow] = av.y;
        As[akq*4+2][arow] = av.z;
        As[akq*4+3][arow] = av.w;
        #pragma unroll
        for (int u = 0; u < 4; ++u) {
            int n = bn + u*16;
            int sw = ((n >> 2) ^ bkk) & 15;
            Bs[bkk][sw*4 + (n & 3)] = bvals[u];
        }
        __syncthreads();
        #pragma unroll
        for (int k = 0; k < 16; ++k) {
            float4 a4 = ld4(&As[k][ty*4]);
            float4 b4 = ld4(&Bs[k][((tx ^ k) & 15) * 4]);
            float aa[4] = {a4.x, a4.y, a4.z, a4.w};
            float bb[4] = {b4.x, b4.y, b4.z, b4.w};
            #pragma unroll
            for (int i = 0; i < 4; ++i)
                #pragma unroll
                for (int j = 0; j < 4; ++j)
                    acc[i][j] = fmaf(aa[i], bb[j], acc[i][j]);
        }
    }
    float4 bb4 = ld4(&bp[n0 + tx*4]);
    #pragma unroll
    for (int i = 0; i < 4; ++i) {
        int m = m0 + ty*4 + i;
        st4(&out[(size_t)m * Cn + n0 + tx*4],
            make_float4(acc[i][0]+bb4.x, acc[i][1]+bb4.y, acc[i][2]+bb4.z, acc[i][3]+bb4.w));
    }
}

extern "C" void kernel_launch(void* const* d_in, const int* in_sizes, int n_in,
                              void* d_out, int out_size, void* d_ws, size_t ws_size,
                              hipStream_t stream) {
    const float* x  = (const float*)d_in[0];
    const float* wq = (const float*)d_in[1];
    const float* wk = (const float*)d_in[2];
    const float* wv = (const float*)d_in[3];
    const float* wp = (const float*)d_in[4];
    const float* bp = (const float*)d_in[5];
    float* out = (float*)d_out;

    float* ws = (float*)d_ws;
    const size_t SZ = (size_t)Bn * Hn * Tn * Dn;   // 6291456
    float* qv = ws;
    float* kv = ws + SZ;
    float* vv = ws + 2*SZ;
    float* at = ws + 3*SZ;                          // [M, C]

    qkv_proj<<<dim3(Mn/64, 3*Hn), 256, 0, stream>>>(x, wq, wk, wv, qv, kv, vv);
    attn_fwd<<<dim3(Bn*Hn*(Tn/64)), 256, 0, stream>>>(qv, kv, vv, at);
    out_proj<<<dim3(Mn/64, Cn/64), 256, 0, stream>>>(at, wp, bp, out);
}

// Round 5
// 192.285 us; speedup vs baseline: 8.0391x; 8.0391x over previous
//
#include <hip/hip_runtime.h>
#include <hip/hip_bf16.h>

// MHA B=16 T=1024 C=384 H=6 D=64 — bf16 MFMA pipeline.
// ws: xb | wt[3][H][D][C] | wpb | qb[B,H,T,D] | kb[B,H,T,D] | vtb[B,H,D,T] | att[M,C]
#define Hn 6
#define Tn 1024
#define Cn 384
#define Dn 64
#define Bn 16
#define Mn (Bn*Tn)
#define QSCALE 0.07362222f   // log2(e)/sqrt(384): folds softmax scale + exp2 conversion into wq

typedef __attribute__((ext_vector_type(8)))  short s16x8;
typedef __attribute__((ext_vector_type(16))) float f32x16;

__device__ __forceinline__ void gl_lds16(const void* g, void* l) {
  __builtin_amdgcn_global_load_lds(
      (const __attribute__((address_space(1))) unsigned int*)g,
      (__attribute__((address_space(3))) unsigned int*)l, 16, 0, 0);
}
__device__ __forceinline__ unsigned pk2f(float a, float b) {
  __hip_bfloat162 h = __float22bfloat162_rn(make_float2(a, b));
  union { __hip_bfloat162 h; unsigned u; } cv; cv.h = h; return cv.u;
}
__device__ __forceinline__ f32x16 mfma32(s16x8 a, s16x8 b, f32x16 c) {
  return __builtin_amdgcn_mfma_f32_32x32x16_bf16(a, b, c, 0, 0, 0);
}

// ---------- convert: x->bf16; w -> bf16 transposed [mat][h][d][c] (wq scaled); wp->bf16 ----------
__global__ __launch_bounds__(256) void convert_all(
    const float* __restrict__ x, const float* __restrict__ wq,
    const float* __restrict__ wk, const float* __restrict__ wv,
    const float* __restrict__ wp,
    __hip_bfloat16* __restrict__ xb, __hip_bfloat16* __restrict__ wt,
    __hip_bfloat16* __restrict__ wpb)
{
  const int bid = blockIdx.x, t = threadIdx.x;
  if (bid < 18) {                       // weight transpose, one (mat,h) per block
    __shared__ float lt[64][65];
    const int mat = bid / Hn, hh = bid % Hn;
    const float* src = (mat == 0 ? wq : mat == 1 ? wk : wv) + (size_t)hh * (Cn*Dn);
    __hip_bfloat16* dst = wt + (size_t)mat * (Hn*Dn*Cn) + (size_t)hh * (Dn*Cn);
    const float sc = (mat == 0) ? QSCALE : 1.0f;
    for (int ct = 0; ct < 6; ++ct) {    // 6 c-tiles of 64
      __syncthreads();
      #pragma unroll
      for (int ps = 0; ps < 4; ++ps) {
        int idx = ps*256 + t;
        int cl = idx >> 4, s4 = idx & 15;
        float4 v = *reinterpret_cast<const float4*>(src + (size_t)(ct*64 + cl)*Dn + s4*4);
        lt[cl][s4*4+0] = v.x * sc; lt[cl][s4*4+1] = v.y * sc;
        lt[cl][s4*4+2] = v.z * sc; lt[cl][s4*4+3] = v.w * sc;
      }
      __syncthreads();
      const int dd = t >> 2, cq = t & 3;
      #pragma unroll
      for (int i = 0; i < 16; ++i)
        dst[(size_t)dd*Cn + ct*64 + cq*16 + i] = __float2bfloat16(lt[cq*16 + i][dd]);
    }
  } else if (bid < 90) {                // wp copy (no transpose: B-operand wants [j][i] rows)
    const size_t base = (size_t)(bid - 18) * 2048 + (size_t)t * 8;
    float4 a = *reinterpret_cast<const float4*>(wp + base);
    float4 b = *reinterpret_cast<const float4*>(wp + base + 4);
    uint4 r; r.x = pk2f(a.x,a.y); r.y = pk2f(a.z,a.w); r.z = pk2f(b.x,b.y); r.w = pk2f(b.z,b.w);
    *reinterpret_cast<uint4*>((char*)wpb + base*2) = r;
  } else {                              // x -> bf16
    const size_t base = (size_t)(bid - 90) * 2048 + (size_t)t * 8;
    float4 a = *reinterpret_cast<const float4*>(x + base);
    float4 b = *reinterpret_cast<const float4*>(x + base + 4);
    uint4 r; r.x = pk2f(a.x,a.y); r.y = pk2f(a.z,a.w); r.z = pk2f(b.x,b.y); r.w = pk2f(b.z,b.w);
    *reinterpret_cast<uint4*>((char*)xb + base*2) = r;
  }
}

// ---------- qkv projection: 64x64 tile, 4 waves (2x2), mfma 32x32x16 ----------
__global__ __launch_bounds__(256) void qkv_proj(
    const __hip_bfloat16* __restrict__ xb, const __hip_bfloat16* __restrict__ wt,
    __hip_bfloat16* __restrict__ qo, __hip_bfloat16* __restrict__ ko,
    __hip_bfloat16* __restrict__ vto)
{
  __shared__ __align__(16) char sm[8192];   // X[64][32]bf16 | W[64][32]bf16, slot16-swizzled
  const int t = threadIdx.x, lane = t & 63, w = t >> 6;
  const int hi = lane >> 5, nl = lane & 31;
  const int wr = w >> 1, wc = w & 1;
  const int m0 = blockIdx.x * 64;
  const int mat = blockIdx.y / Hn, h = blockIdx.y % Hn;
  const __hip_bfloat16* wb = wt + (size_t)mat*(Hn*Dn*Cn) + (size_t)h*(Dn*Cn);

  const int mrow = wr*32 + nl;
  const int nrow = wc*32 + nl;
  f32x16 acc = {};
  for (int k0 = 0; k0 < Cn; k0 += 32) {
    __syncthreads();
    #pragma unroll
    for (int c = 0; c < 2; ++c) {
      const int off = w*2048 + c*1024 + lane*16;
      const char* src;
      if (off < 4096) {
        const int row = off >> 6, sl = (off >> 4) & 3;
        src = (const char*)(xb + (size_t)(m0 + row)*Cn + k0) + ((sl ^ (row & 3)) * 16);
      } else {
        const int o2 = off - 4096;
        const int row = o2 >> 6, sl = (o2 >> 4) & 3;
        src = (const char*)(wb + (size_t)row*Cn + k0) + ((sl ^ (row & 3)) * 16);
      }
      gl_lds16(src, sm + w*2048 + c*1024);
    }
    __syncthreads();
    #pragma unroll
    for (int kk = 0; kk < 2; ++kk) {
      s16x8 a  = *reinterpret_cast<const s16x8*>(sm + mrow*64 + (((2*kk + hi) ^ (mrow & 3)) * 16));
      s16x8 bb = *reinterpret_cast<const s16x8*>(sm + 4096 + nrow*64 + (((2*kk + hi) ^ (nrow & 3)) * 16));
      acc = mfma32(a, bb, acc);
    }
  }
  // C layout: col = nl, row = (r&3)+8*(r>>2)+4*hi  [m74/m101]
  const int d = wc*32 + nl;
  if (mat < 2) {
    __hip_bfloat16* op = (mat == 0) ? qo : ko;
    #pragma unroll
    for (int r = 0; r < 16; ++r) {
      const int ml = wr*32 + (r & 3) + 8*(r >> 2) + 4*hi;
      const int M = m0 + ml, bI = M >> 10, tl = M & 1023;
      op[(((size_t)bI*Hn + h)*Tn + tl)*Dn + d] = __float2bfloat16(acc[r]);
    }
  } else {                               // V transposed: vto[b,h,d,t]
    #pragma unroll
    for (int rq = 0; rq < 4; ++rq) {
      const int ml = wr*32 + 8*rq + 4*hi;
      const int M = m0 + ml, bI = M >> 10, tl = M & 1023;
      const unsigned u0 = pk2f(acc[rq*4+0], acc[rq*4+1]);
      const unsigned u1 = pk2f(acc[rq*4+2], acc[rq*4+3]);
      const unsigned long long v = ((unsigned long long)u1 << 32) | u0;
      *reinterpret_cast<unsigned long long*>(
          (char*)vto + ((((size_t)bI*Hn + h)*Dn + d)*Tn + tl)*2) = v;
    }
  }
}

// ---------- attention: QB=128 (4 waves x 32q), KV tiles 64, swapped QK^T, no max-sub ----------
__global__ __launch_bounds__(256) void attn_fwd(
    const __hip_bfloat16* __restrict__ qb, const __hip_bfloat16* __restrict__ kb,
    const __hip_bfloat16* __restrict__ vtb, __hip_bfloat16* __restrict__ ao)
{
  __shared__ __align__(16) char smem[16384];    // K[64][64]bf16 | VT[64][64]bf16 (slot16 ^ row&7)
  const int t = threadIdx.x, lane = t & 63, w = t >> 6;
  const int hi = lane >> 5, qm = lane & 31;
  const int l7 = lane & 7;
  const int bh = blockIdx.x >> 3, qt = blockIdx.x & 7;
  const int b = bh / Hn, h = bh % Hn;

  // Q fragments (pre-scaled bf16) straight from global: q row, d = 16h'+8hi+j
  const int qrow = qt*128 + w*32 + qm;
  const __hip_bfloat16* qrp = qb + ((size_t)bh*Tn + qrow)*Dn;
  s16x8 qf[4];
  #pragma unroll
  for (int hh = 0; hh < 4; ++hh)
    qf[hh] = *reinterpret_cast<const s16x8*>(qrp + hh*16 + hi*8);

  const size_t kbase = (size_t)bh * Tn * Dn;
  const size_t vbase = (size_t)bh * Dn * Tn;

  f32x16 oacc[2] = {};
  float lsum = 0.f;

  for (int kt = 0; kt < 16; ++kt) {
    __syncthreads();
    #pragma unroll
    for (int c = 0; c < 4; ++c) {          // stage K (0..8K) + VT (8..16K), pre-swizzled source
      const int off = w*4096 + c*1024 + lane*16;
      const char* src;
      if (off < 8192) {
        const int row = off >> 7, sl = (off >> 4) & 7;
        src = (const char*)(kb + kbase + (size_t)(kt*64 + row)*Dn) + ((sl ^ (row & 7)) * 16);
      } else {
        const int o2 = off - 8192;
        const int row = o2 >> 7, sl = (o2 >> 4) & 7;
        src = (const char*)(vtb + vbase + (size_t)row*Tn + kt*64) + ((sl ^ (row & 7)) * 16);
      }
      gl_lds16(src, smem + w*4096 + c*1024);
    }
    __syncthreads();

    // S^T = mfma(K, Q): D[s][q], wave covers s 0..63 (2 tiles) x its 32 q
    f32x16 sacc[2] = {};
    #pragma unroll
    for (int ts = 0; ts < 2; ++ts) {
      const int srow = ts*32 + qm;
      #pragma unroll
      for (int hh = 0; hh < 4; ++hh) {
        s16x8 ka = *reinterpret_cast<const s16x8*>(
            smem + srow*128 + (((2*hh + hi) ^ l7) * 16));
        sacc[ts] = mfma32(ka, qf[hh], sacc[ts]);
      }
    }
    // p = exp2(s) in place (scale folded into Q); accumulate denominator
    #pragma unroll
    for (int ts = 0; ts < 2; ++ts)
      #pragma unroll
      for (int r = 0; r < 16; ++r) { float p = exp2f(sacc[ts][r]); sacc[ts][r] = p; lsum += p; }

    // build P^T B-frags (k = s = 16m+8hi+j) via one cross-half exchange per m; PV mfma
    #pragma unroll
    for (int m = 0; m < 4; ++m) {
      const int ts = m >> 1, rb = 8*(m & 1);
      const unsigned A0 = pk2f(sacc[ts][rb+0], sacc[ts][rb+1]);
      const unsigned A1 = pk2f(sacc[ts][rb+2], sacc[ts][rb+3]);
      const unsigned B0 = pk2f(sacc[ts][rb+4], sacc[ts][rb+5]);
      const unsigned B1 = pk2f(sacc[ts][rb+6], sacc[ts][rb+7]);
      const unsigned s0 = hi ? A0 : B0;      // send what the partner half needs
      const unsigned s1 = hi ? A1 : B1;
      const unsigned r0 = __shfl_xor(s0, 32);
      const unsigned r1 = __shfl_xor(s1, 32);
      union { unsigned u[4]; s16x8 v; } fr;
      fr.u[0] = hi ? r0 : A0;  fr.u[1] = hi ? r1 : A1;
      fr.u[2] = hi ? B0 : r0;  fr.u[3] = hi ? B1 : r1;
      #pragma unroll
      for (int dt = 0; dt < 2; ++dt) {
        const int drow = dt*32 + qm;
        s16x8 va = *reinterpret_cast<const s16x8*>(
            smem + 8192 + drow*128 + (((2*m + hi) ^ l7) * 16));
        oacc[dt] = mfma32(va, fr.v, oacc[dt]);
      }
    }
  }

  lsum += __shfl_xor(lsum, 32);
  const float inv = 1.0f / lsum;

  // epilogue: OT -> LDS (swizzled) -> coalesced bf16 rows of att[M][C]
  __syncthreads();
  const int qloc = w*32 + qm;
  #pragma unroll
  for (int dt = 0; dt < 2; ++dt)
    #pragma unroll
    for (int rq = 0; rq < 4; ++rq) {
      const unsigned u0 = pk2f(oacc[dt][rq*4+0]*inv, oacc[dt][rq*4+1]*inv);
      const unsigned u1 = pk2f(oacc[dt][rq*4+2]*inv, oacc[dt][rq*4+3]*inv);
      const unsigned long long v = ((unsigned long long)u1 << 32) | u0;
      *reinterpret_cast<unsigned long long*>(
          smem + qloc*128 + (((4*dt + rq) ^ (qm & 7)) * 16) + 8*hi) = v;
    }
  __syncthreads();
  {
    const int qr = t >> 1, half = t & 1;
    char* dst = (char*)ao + ((size_t)(b*Tn + qt*128 + qr))*(Cn*2) + (h*Dn + half*32)*2;
    #pragma unroll
    for (int sl = 0; sl < 4; ++sl) {
      uint4 v = *reinterpret_cast<const uint4*>(
          smem + qr*128 + (((half*4 + sl) ^ (qr & 7)) * 16));
      *reinterpret_cast<uint4*>(dst + sl*16) = v;
    }
  }
}

// ---------- output projection + bias ----------
__global__ __launch_bounds__(256) void out_proj(
    const __hip_bfloat16* __restrict__ ab, const __hip_bfloat16* __restrict__ wpb,
    const float* __restrict__ bp, float* __restrict__ out)
{
  __shared__ __align__(16) char sm[8192];
  const int t = threadIdx.x, lane = t & 63, w = t >> 6;
  const int hi = lane >> 5, nl = lane & 31;
  const int wr = w >> 1, wc = w & 1;
  const int m0 = blockIdx.x * 64;
  const int n0 = blockIdx.y * 64;

  const int mrow = wr*32 + nl;
  const int nrow = wc*32 + nl;
  f32x16 acc = {};
  for (int k0 = 0; k0 < Cn; k0 += 32) {
    __syncthreads();
    #pragma unroll
    for (int c = 0; c < 2; ++c) {
      const int off = w*2048 + c*1024 + lane*16;
      const char* src;
      if (off < 4096) {
        const int row = off >> 6, sl = (off >> 4) & 3;
        src = (const char*)(ab + (size_t)(m0 + row)*Cn + k0) + ((sl ^ (row & 3)) * 16);
      } else {
        const int o2 = off - 4096;
        const int row = o2 >> 6, sl = (o2 >> 4) & 3;
        src = (const char*)(wpb + (size_t)(n0 + row)*Cn + k0) + ((sl ^ (row & 3)) * 16);
      }
      gl_lds16(src, sm + w*2048 + c*1024);
    }
    __syncthreads();
    #pragma unroll
    for (int kk = 0; kk < 2; ++kk) {
      s16x8 a  = *reinterpret_cast<const s16x8*>(sm + mrow*64 + (((2*kk + hi) ^ (mrow & 3)) * 16));
      s16x8 bb = *reinterpret_cast<const s16x8*>(sm + 4096 + nrow*64 + (((2*kk + hi) ^ (nrow & 3)) * 16));
      acc = mfma32(a, bb, acc);
    }
  }
  const int n = n0 + wc*32 + nl;
  const float bv = bp[n];
  #pragma unroll
  for (int r = 0; r < 16; ++r) {
    const int ml = wr*32 + (r & 3) + 8*(r >> 2) + 4*hi;
    out[(size_t)(m0 + ml)*Cn + n] = acc[r] + bv;
  }
}

extern "C" void kernel_launch(void* const* d_in, const int* in_sizes, int n_in,
                              void* d_out, int out_size, void* d_ws, size_t ws_size,
                              hipStream_t stream) {
  const float* x  = (const float*)d_in[0];
  const float* wq = (const float*)d_in[1];
  const float* wk = (const float*)d_in[2];
  const float* wv = (const float*)d_in[3];
  const float* wp = (const float*)d_in[4];
  const float* bp = (const float*)d_in[5];
  float* out = (float*)d_out;

  unsigned char* W = (unsigned char*)d_ws;
  __hip_bfloat16* xb  = (__hip_bfloat16*)(W);               // 12,582,912 B
  __hip_bfloat16* wt  = (__hip_bfloat16*)(W + 12582912);    //    884,736 B  [3][H][D][C]
  __hip_bfloat16* wpb = (__hip_bfloat16*)(W + 13467648);    //    294,912 B
  __hip_bfloat16* qv  = (__hip_bfloat16*)(W + 13762560);    // 12,582,912 B
  __hip_bfloat16* kv  = (__hip_bfloat16*)(W + 26345472);    // 12,582,912 B
  __hip_bfloat16* vt  = (__hip_bfloat16*)(W + 38928384);    // 12,582,912 B
  __hip_bfloat16* at  = (__hip_bfloat16*)(W + 51511296);    // 12,582,912 B -> ends 64,094,208

  convert_all<<<3162, 256, 0, stream>>>(x, wq, wk, wv, wp, xb, wt, wpb);
  qkv_proj<<<dim3(Mn/64, 3*Hn), 256, 0, stream>>>(xb, wt, qv, kv, vt);
  attn_fwd<<<Bn*Hn*(Tn/128), 256, 0, stream>>>(qv, kv, vt, at);
  out_proj<<<dim3(Mn/64, Cn/64), 256, 0, stream>>>(at, wpb, bp, out);
}

// Round 6
// 183.454 us; speedup vs baseline: 8.4261x; 1.0481x over previous
//
#include <hip/hip_runtime.h>
#include <hip/hip_bf16.h>

// MHA B=16 T=1024 C=384 H=6 D=64 — bf16 MFMA pipeline, 2-phase dbuf staging.
#define Hn 6
#define Tn 1024
#define Cn 384
#define Dn 64
#define Bn 16
#define Mn (Bn*Tn)
#define QSCALE 0.07362222f   // log2(e)/sqrt(384): folds softmax scale + exp2 conversion into wq

typedef __attribute__((ext_vector_type(8)))  short s16x8;
typedef __attribute__((ext_vector_type(16))) float f32x16;

__device__ __forceinline__ void gl_lds16(const void* g, void* l) {
  __builtin_amdgcn_global_load_lds(
      (const __attribute__((address_space(1))) unsigned int*)g,
      (__attribute__((address_space(3))) unsigned int*)l, 16, 0, 0);
}
__device__ __forceinline__ unsigned pk2f(float a, float b) {
  __hip_bfloat162 h = __float22bfloat162_rn(make_float2(a, b));
  union { __hip_bfloat162 h; unsigned u; } cv; cv.h = h; return cv.u;
}
__device__ __forceinline__ f32x16 mfma32(s16x8 a, s16x8 b, f32x16 c) {
  return __builtin_amdgcn_mfma_f32_32x32x16_bf16(a, b, c, 0, 0, 0);
}

// ---------- convert: x->bf16; w -> bf16 transposed [mat][h][d][c] (wq scaled); wp->bf16 ----------
__global__ __launch_bounds__(256) void convert_all(
    const float* __restrict__ x, const float* __restrict__ wq,
    const float* __restrict__ wk, const float* __restrict__ wv,
    const float* __restrict__ wp,
    __hip_bfloat16* __restrict__ xb, __hip_bfloat16* __restrict__ wt,
    __hip_bfloat16* __restrict__ wpb)
{
  const int bid = blockIdx.x, t = threadIdx.x;
  if (bid < 18) {                       // weight transpose, one (mat,h) per block
    __shared__ float lt[64][65];
    const int mat = bid / Hn, hh = bid % Hn;
    const float* src = (mat == 0 ? wq : mat == 1 ? wk : wv) + (size_t)hh * (Cn*Dn);
    __hip_bfloat16* dst = wt + (size_t)mat * (Hn*Dn*Cn) + (size_t)hh * (Dn*Cn);
    const float sc = (mat == 0) ? QSCALE : 1.0f;
    for (int ct = 0; ct < 6; ++ct) {    // 6 c-tiles of 64
      __syncthreads();
      #pragma unroll
      for (int ps = 0; ps < 4; ++ps) {
        int idx = ps*256 + t;
        int cl = idx >> 4, s4 = idx & 15;
        float4 v = *reinterpret_cast<const float4*>(src + (size_t)(ct*64 + cl)*Dn + s4*4);
        lt[cl][s4*4+0] = v.x * sc; lt[cl][s4*4+1] = v.y * sc;
        lt[cl][s4*4+2] = v.z * sc; lt[cl][s4*4+3] = v.w * sc;
      }
      __syncthreads();
      const int dd = t >> 2, cq = t & 3;
      #pragma unroll
      for (int i = 0; i < 16; ++i)
        dst[(size_t)dd*Cn + ct*64 + cq*16 + i] = __float2bfloat16(lt[cq*16 + i][dd]);
    }
  } else if (bid < 90) {                // wp copy (no transpose: B-operand wants [j][i] rows)
    const size_t base = (size_t)(bid - 18) * 2048 + (size_t)t * 8;
    float4 a = *reinterpret_cast<const float4*>(wp + base);
    float4 b = *reinterpret_cast<const float4*>(wp + base + 4);
    uint4 r; r.x = pk2f(a.x,a.y); r.y = pk2f(a.z,a.w); r.z = pk2f(b.x,b.y); r.w = pk2f(b.z,b.w);
    *reinterpret_cast<uint4*>((char*)wpb + base*2) = r;
  } else {                              // x -> bf16
    const size_t base = (size_t)(bid - 90) * 2048 + (size_t)t * 8;
    float4 a = *reinterpret_cast<const float4*>(x + base);
    float4 b = *reinterpret_cast<const float4*>(x + base + 4);
    uint4 r; r.x = pk2f(a.x,a.y); r.y = pk2f(a.z,a.w); r.z = pk2f(b.x,b.y); r.w = pk2f(b.z,b.w);
    *reinterpret_cast<uint4*>((char*)xb + base*2) = r;
  }
}

// ---------- qkv projection: 64x64 tile, BK=64, 2-phase dbuf, mfma 32x32x16 ----------
__global__ __launch_bounds__(256) void qkv_proj(
    const __hip_bfloat16* __restrict__ xb, const __hip_bfloat16* __restrict__ wt,
    __hip_bfloat16* __restrict__ qo, __hip_bfloat16* __restrict__ ko,
    __hip_bfloat16* __restrict__ vto)
{
  __shared__ __align__(16) char sm[32768];  // 2 x (X[64][64] | W[64][64]), slot16 ^ (row&7)
  const int t = threadIdx.x, lane = t & 63, w = t >> 6;
  const int hi = lane >> 5, nl = lane & 31;
  const int wr = w >> 1, wc = w & 1;
  const int m0 = blockIdx.x * 64;
  const int mat = blockIdx.y / Hn, h = blockIdx.y % Hn;
  const __hip_bfloat16* wb = wt + (size_t)mat*(Hn*Dn*Cn) + (size_t)h*(Dn*Cn);

  const int mrow = wr*32 + nl;
  const int nrow = wc*32 + nl;
  f32x16 acc = {};

  auto stage = [&](int bb, int s) {       // stage k-step s (k0 = s*64) into buffer bb
    #pragma unroll
    for (int c = 0; c < 4; ++c) {
      const int off = w*4096 + c*1024 + lane*16;
      const char* src;
      if (off < 8192) {
        const int row = off >> 7, sl = (off >> 4) & 7;
        src = (const char*)xb + (size_t)(m0 + row)*768 + s*128 + ((sl ^ (row & 7)) * 16);
      } else {
        const int o2 = off - 8192;
        const int row = o2 >> 7, sl = (o2 >> 4) & 7;
        src = (const char*)wb + (size_t)row*768 + s*128 + ((sl ^ (row & 7)) * 16);
      }
      gl_lds16(src, sm + bb + w*4096 + c*1024);
    }
  };
  auto compute = [&](int bb) {
    __builtin_amdgcn_s_setprio(1);
    #pragma unroll
    for (int kk = 0; kk < 4; ++kk) {
      s16x8 a  = *reinterpret_cast<const s16x8*>(sm + bb + mrow*128 + (((2*kk + hi) ^ (mrow & 7)) * 16));
      s16x8 bv = *reinterpret_cast<const s16x8*>(sm + bb + 8192 + nrow*128 + (((2*kk + hi) ^ (nrow & 7)) * 16));
      acc = mfma32(a, bv, acc);
    }
    __builtin_amdgcn_s_setprio(0);
  };

  stage(0, 0);
  __syncthreads();
  for (int s = 0; s < 6; s += 2) {
    stage(16384, s + 1);
    compute(0);
    __syncthreads();
    if (s + 2 < 6) stage(0, s + 2);
    compute(16384);
    __syncthreads();
  }

  // C layout: col = nl, row = (r&3)+8*(r>>2)+4*hi  [m74/m101]
  const int d = wc*32 + nl;
  if (mat < 2) {
    __hip_bfloat16* op = (mat == 0) ? qo : ko;
    #pragma unroll
    for (int r = 0; r < 16; ++r) {
      const int ml = wr*32 + (r & 3) + 8*(r >> 2) + 4*hi;
      const int M = m0 + ml, bI = M >> 10, tl = M & 1023;
      op[(((size_t)bI*Hn + h)*Tn + tl)*Dn + d] = __float2bfloat16(acc[r]);
    }
  } else {                               // V transposed: vto[b,h,d,t]
    #pragma unroll
    for (int rq = 0; rq < 4; ++rq) {
      const int ml = wr*32 + 8*rq + 4*hi;
      const int M = m0 + ml, bI = M >> 10, tl = M & 1023;
      const unsigned u0 = pk2f(acc[rq*4+0], acc[rq*4+1]);
      const unsigned u1 = pk2f(acc[rq*4+2], acc[rq*4+3]);
      const unsigned long long v = ((unsigned long long)u1 << 32) | u0;
      *reinterpret_cast<unsigned long long*>(
          (char*)vto + ((((size_t)bI*Hn + h)*Dn + d)*Tn + tl)*2) = v;
    }
  }
}

// ---------- attention: QB=128 (4 waves x 32q), KV tiles 64, dbuf, swapped QK^T, no max-sub ----------
// Block swizzle: bh = bx%96, qt = bx/96 -> the 8 qt-blocks of one (b,h) share an XCD (96%8==0).
__global__ __launch_bounds__(256) void attn_fwd(
    const __hip_bfloat16* __restrict__ qb, const __hip_bfloat16* __restrict__ kb,
    const __hip_bfloat16* __restrict__ vtb, __hip_bfloat16* __restrict__ ao)
{
  __shared__ __align__(16) char smem[32768];   // 2 x (K[64][64] | VT[64][64]), slot16 ^ (row&7)
  const int t = threadIdx.x, lane = t & 63, w = t >> 6;
  const int hi = lane >> 5, qm = lane & 31;
  const int l7 = lane & 7;
  const int bx = blockIdx.x;
  const int bh = bx % 96, qt = bx / 96;        // XCD-grouping swizzle
  const int b = bh / Hn, h = bh % Hn;

  // Q fragments (pre-scaled bf16) straight from global
  const int qrow = qt*128 + w*32 + qm;
  const __hip_bfloat16* qrp = qb + ((size_t)bh*Tn + qrow)*Dn;
  s16x8 qf[4];
  #pragma unroll
  for (int hh = 0; hh < 4; ++hh)
    qf[hh] = *reinterpret_cast<const s16x8*>(qrp + hh*16 + hi*8);

  const size_t kbase = (size_t)bh * Tn * Dn;
  const size_t vbase = (size_t)bh * Dn * Tn;

  f32x16 oacc[2] = {};
  float lsum = 0.f;

  auto stage = [&](int bb, int kt) {
    #pragma unroll
    for (int c = 0; c < 4; ++c) {
      const int off = w*4096 + c*1024 + lane*16;
      const char* src;
      if (off < 8192) {
        const int row = off >> 7, sl = (off >> 4) & 7;
        src = (const char*)(kb + kbase + (size_t)(kt*64 + row)*Dn) + ((sl ^ (row & 7)) * 16);
      } else {
        const int o2 = off - 8192;
        const int row = o2 >> 7, sl = (o2 >> 4) & 7;
        src = (const char*)(vtb + vbase + (size_t)row*Tn + kt*64) + ((sl ^ (row & 7)) * 16);
      }
      gl_lds16(src, smem + bb + w*4096 + c*1024);
    }
  };

  auto compute = [&](int bb) {
    // S^T = mfma(K, Q): D[s][q], wave covers s 0..63 (2 tiles) x its 32 q
    f32x16 sacc[2] = {};
    __builtin_amdgcn_s_setprio(1);
    #pragma unroll
    for (int ts = 0; ts < 2; ++ts) {
      const int srow = ts*32 + qm;
      #pragma unroll
      for (int hh = 0; hh < 4; ++hh) {
        s16x8 ka = *reinterpret_cast<const s16x8*>(
            smem + bb + srow*128 + (((2*hh + hi) ^ l7) * 16));
        sacc[ts] = mfma32(ka, qf[hh], sacc[ts]);
      }
    }
    __builtin_amdgcn_s_setprio(0);
    // p = exp2(s) (scale folded into Q); accumulate denominator
    #pragma unroll
    for (int ts = 0; ts < 2; ++ts)
      #pragma unroll
      for (int r = 0; r < 16; ++r) { float p = exp2f(sacc[ts][r]); sacc[ts][r] = p; lsum += p; }

    // build P^T B-frags (k = s = 16m+8hi+j) via one cross-half exchange per m; PV mfma
    #pragma unroll
    for (int m = 0; m < 4; ++m) {
      const int ts = m >> 1, rb = 8*(m & 1);
      const unsigned A0 = pk2f(sacc[ts][rb+0], sacc[ts][rb+1]);
      const unsigned A1 = pk2f(sacc[ts][rb+2], sacc[ts][rb+3]);
      const unsigned B0 = pk2f(sacc[ts][rb+4], sacc[ts][rb+5]);
      const unsigned B1 = pk2f(sacc[ts][rb+6], sacc[ts][rb+7]);
      const unsigned s0 = hi ? A0 : B0;      // send what the partner half needs
      const unsigned s1 = hi ? A1 : B1;
      const unsigned r0 = __shfl_xor(s0, 32);
      const unsigned r1 = __shfl_xor(s1, 32);
      union { unsigned u[4]; s16x8 v; } fr;
      fr.u[0] = hi ? r0 : A0;  fr.u[1] = hi ? r1 : A1;
      fr.u[2] = hi ? B0 : r0;  fr.u[3] = hi ? B1 : r1;
      __builtin_amdgcn_s_setprio(1);
      #pragma unroll
      for (int dt = 0; dt < 2; ++dt) {
        const int drow = dt*32 + qm;
        s16x8 va = *reinterpret_cast<const s16x8*>(
            smem + bb + 8192 + drow*128 + (((2*m + hi) ^ l7) * 16));
        oacc[dt] = mfma32(va, fr.v, oacc[dt]);
      }
      __builtin_amdgcn_s_setprio(0);
    }
  };

  stage(0, 0);
  __syncthreads();
  for (int kt = 0; kt < 16; kt += 2) {
    stage(16384, kt + 1);               // kt+1 <= 15 always inside loop
    compute(0);
    __syncthreads();
    if (kt + 2 < 16) stage(0, kt + 2);
    compute(16384);
    __syncthreads();
  }

  lsum += __shfl_xor(lsum, 32);
  const float inv = 1.0f / lsum;

  // epilogue: OT -> LDS (swizzled, reuse buf0) -> coalesced bf16 rows of att[M][C]
  const int qloc = w*32 + qm;
  #pragma unroll
  for (int dt = 0; dt < 2; ++dt)
    #pragma unroll
    for (int rq = 0; rq < 4; ++rq) {
      const unsigned u0 = pk2f(oacc[dt][rq*4+0]*inv, oacc[dt][rq*4+1]*inv);
      const unsigned u1 = pk2f(oacc[dt][rq*4+2]*inv, oacc[dt][rq*4+3]*inv);
      const unsigned long long v = ((unsigned long long)u1 << 32) | u0;
      *reinterpret_cast<unsigned long long*>(
          smem + qloc*128 + (((4*dt + rq) ^ (qm & 7)) * 16) + 8*hi) = v;
    }
  __syncthreads();
  {
    const int qr = t >> 1, half = t & 1;
    char* dst = (char*)ao + ((size_t)(b*Tn + qt*128 + qr))*(Cn*2) + (h*Dn + half*32)*2;
    #pragma unroll
    for (int sl = 0; sl < 4; ++sl) {
      uint4 v = *reinterpret_cast<const uint4*>(
          smem + qr*128 + (((half*4 + sl) ^ (qr & 7)) * 16));
      *reinterpret_cast<uint4*>(dst + sl*16) = v;
    }
  }
}

// ---------- output projection + bias: BK=64, 2-phase dbuf ----------
__global__ __launch_bounds__(256) void out_proj(
    const __hip_bfloat16* __restrict__ ab, const __hip_bfloat16* __restrict__ wpb,
    const float* __restrict__ bp, float* __restrict__ out)
{
  __shared__ __align__(16) char sm[32768];
  const int t = threadIdx.x, lane = t & 63, w = t >> 6;
  const int hi = lane >> 5, nl = lane & 31;
  const int wr = w >> 1, wc = w & 1;
  const int m0 = blockIdx.x * 64;
  const int n0 = blockIdx.y * 64;

  const int mrow = wr*32 + nl;
  const int nrow = wc*32 + nl;
  f32x16 acc = {};

  auto stage = [&](int bb, int s) {
    #pragma unroll
    for (int c = 0; c < 4; ++c) {
      const int off = w*4096 + c*1024 + lane*16;
      const char* src;
      if (off < 8192) {
        const int row = off >> 7, sl = (off >> 4) & 7;
        src = (const char*)ab + (size_t)(m0 + row)*768 + s*128 + ((sl ^ (row & 7)) * 16);
      } else {
        const int o2 = off - 8192;
        const int row = o2 >> 7, sl = (o2 >> 4) & 7;
        src = (const char*)wpb + (size_t)(n0 + row)*768 + s*128 + ((sl ^ (row & 7)) * 16);
      }
      gl_lds16(src, sm + bb + w*4096 + c*1024);
    }
  };
  auto compute = [&](int bb) {
    __builtin_amdgcn_s_setprio(1);
    #pragma unroll
    for (int kk = 0; kk < 4; ++kk) {
      s16x8 a  = *reinterpret_cast<const s16x8*>(sm + bb + mrow*128 + (((2*kk + hi) ^ (mrow & 7)) * 16));
      s16x8 bv = *reinterpret_cast<const s16x8*>(sm + bb + 8192 + nrow*128 + (((2*kk + hi) ^ (nrow & 7)) * 16));
      acc = mfma32(a, bv, acc);
    }
    __builtin_amdgcn_s_setprio(0);
  };

  stage(0, 0);
  __syncthreads();
  for (int s = 0; s < 6; s += 2) {
    stage(16384, s + 1);
    compute(0);
    __syncthreads();
    if (s + 2 < 6) stage(0, s + 2);
    compute(16384);
    __syncthreads();
  }

  const int n = n0 + wc*32 + nl;
  const float bv = bp[n];
  #pragma unroll
  for (int r = 0; r < 16; ++r) {
    const int ml = wr*32 + (r & 3) + 8*(r >> 2) + 4*hi;
    out[(size_t)(m0 + ml)*Cn + n] = acc[r] + bv;
  }
}

extern "C" void kernel_launch(void* const* d_in, const int* in_sizes, int n_in,
                              void* d_out, int out_size, void* d_ws, size_t ws_size,
                              hipStream_t stream) {
  const float* x  = (const float*)d_in[0];
  const float* wq = (const float*)d_in[1];
  const float* wk = (const float*)d_in[2];
  const float* wv = (const float*)d_in[3];
  const float* wp = (const float*)d_in[4];
  const float* bp = (const float*)d_in[5];
  float* out = (float*)d_out;

  unsigned char* W = (unsigned char*)d_ws;
  __hip_bfloat16* xb  = (__hip_bfloat16*)(W);               // 12,582,912 B
  __hip_bfloat16* wt  = (__hip_bfloat16*)(W + 12582912);    //    884,736 B  [3][H][D][C]
  __hip_bfloat16* wpb = (__hip_bfloat16*)(W + 13467648);    //    294,912 B
  __hip_bfloat16* qv  = (__hip_bfloat16*)(W + 13762560);    // 12,582,912 B
  __hip_bfloat16* kv  = (__hip_bfloat16*)(W + 26345472);    // 12,582,912 B
  __hip_bfloat16* vt  = (__hip_bfloat16*)(W + 38928384);    // 12,582,912 B
  __hip_bfloat16* at  = (__hip_bfloat16*)(W + 51511296);    // 12,582,912 B -> ends 64,094,208

  convert_all<<<3162, 256, 0, stream>>>(x, wq, wk, wv, wp, xb, wt, wpb);
  qkv_proj<<<dim3(Mn/64, 3*Hn), 256, 0, stream>>>(xb, wt, qv, kv, vt);
  attn_fwd<<<Bn*Hn*(Tn/128), 256, 0, stream>>>(qv, kv, vt, at);
  out_proj<<<dim3(Mn/64, Cn/64), 256, 0, stream>>>(at, wpb, bp, out);
}